// Round 13
// baseline (221.197 us; speedup 1.0000x reference)
//
#include <hip/hip_runtime.h>

typedef __bf16 bf16x8 __attribute__((ext_vector_type(8)));
typedef float f32x4 __attribute__((ext_vector_type(4)));

#define NEV 16384
#define MTOT 147456      // NEV * 9
#define LDQ 2304         // Bo2 row stride
#define LDX 6912         // 9 * 3 * 256: X[e][p][{q,v,h}][n]

__device__ __forceinline__ unsigned short f2bf(float f) {
  unsigned x = __float_as_uint(f);
  x += 0x7FFFu + ((x >> 16) & 1u);
  return (unsigned short)(x >> 16);
}
__device__ __forceinline__ float bf2f(unsigned short u) {
  return __uint_as_float(((unsigned)u) << 16);
}
__device__ __forceinline__ void load_lds16(const void* g, void* l) {
  __builtin_amdgcn_global_load_lds(
      (const __attribute__((address_space(1))) unsigned int*)g,
      (__attribute__((address_space(3))) unsigned int*)l, 16, 0, 0);
}

// ---------------- per-block seg_start dtype detection ----------------
// mode 0: int32 {0,1}; mode 1: uint8/bool; mode 2: float {0.0,1.0}
__device__ __forceinline__ int derive_mode(const void* seg, int* s_mode) {
  if (threadIdx.x == 0) *s_mode = 0;
  __syncthreads();
  const unsigned int* w = (const unsigned int*)seg;
  int lf = 0, lg = 0;
  for (int i = threadIdx.x; i < 1024; i += blockDim.x) {
    unsigned v = w[i];
    if (v == 0x3F800000u) lf = 1;
    else if (v > 1u) lg = 1;
  }
  if (lf) atomicOr(s_mode, 2);
  if (lg) atomicOr(s_mode, 1);
  __syncthreads();
  int m = *s_mode;
  return (m & 2) ? 2 : ((m & 1) ? 1 : 0);
}

__device__ __forceinline__ bool is_start(const void* seg, int mode, int i) {
  if (mode == 1) return ((const unsigned char*)seg)[i] != 0;
  if (mode == 2) return ((const float*)seg)[i] != 0.0f;
  return ((const int*)seg)[i] != 0;
}

// ---------------- fused casts (events / qvg weights / gather weights) ----------------
__global__ void k_prep(const float* __restrict__ events, const float* __restrict__ q,
                       const float* __restrict__ v, const float* __restrict__ g,
                       const float* __restrict__ gaw,
                       unsigned short* __restrict__ ev_bf, unsigned short* __restrict__ qvgw,
                       unsigned short* __restrict__ gaw_bf) {
  int i = blockIdx.x * blockDim.x + threadIdx.x;
  const float* src;
  unsigned short* dst;
  int off;
  if (i < 1048576) { src = events; dst = ev_bf; off = i; }
  else if (i < 1097728) {
    int j = i - 1048576;
    int w = j >> 14;
    src = (w == 0) ? q : (w == 1) ? v : g;
    dst = qvgw + (long)w * 65536;
    off = j & 16383;
  } else if (i < 1245184) { src = gaw; dst = gaw_bf; off = i - 1097728; }
  else return;
  float4 val = reinterpret_cast<const float4*>(src)[off];
  ushort4 o;
  o.x = f2bf(val.x); o.y = f2bf(val.y); o.z = f2bf(val.z); o.w = f2bf(val.w);
  reinterpret_cast<ushort4*>(dst)[off] = o;
}

// ---------------- LDS-tiled transpose: out[b][r][c] = bf16(in[b][c][r]) ----------------
__global__ __launch_bounds__(256) void k_transpose_t(const float* __restrict__ sw,
                                                     const float* __restrict__ ow,
                                                     unsigned short* __restrict__ wt,
                                                     unsigned short* __restrict__ owt) {
  __shared__ float s[32][33];
  const int z = blockIdx.z;
  const float* src = (z < 9) ? sw + (long)z * 65536 : ow;
  unsigned short* dst = (z < 9) ? wt + (long)z * 65536 : owt;
  const int r0 = blockIdx.x * 32, c0 = blockIdx.y * 32;
  const int tx = threadIdx.x & 31, ty = threadIdx.x >> 5;
#pragma unroll
  for (int cc = 0; cc < 4; ++cc)
    s[ty + cc * 8][tx] = src[(c0 + ty + cc * 8) * 256 + r0 + tx];
  __syncthreads();
#pragma unroll
  for (int cc = 0; cc < 4; ++cc)
    dst[(long)(r0 + ty + cc * 8) * 256 + c0 + tx] = f2bf(s[tx][ty + cc * 8]);
}

// ---------------- ordered segment compaction (deterministic) ----------------
__global__ __launch_bounds__(256) void k_count(const void* __restrict__ seg,
                                               int* __restrict__ blockCounts) {
  __shared__ int wc[4];
  __shared__ int s_mode;
  const int md = derive_mode(seg, &s_mode);
  const int i = blockIdx.x * 256 + threadIdx.x;
  const bool f = is_start(seg, md, i);
  unsigned long long m = __ballot(f);
  const int lane = threadIdx.x & 63, wid = threadIdx.x >> 6;
  if (lane == 0) wc[wid] = __popcll(m);
  __syncthreads();
  if (threadIdx.x == 0) blockCounts[blockIdx.x] = wc[0] + wc[1] + wc[2] + wc[3];
}

__global__ __launch_bounds__(256) void k_emit(const void* __restrict__ seg,
                                              const int* __restrict__ blockCounts,
                                              int* __restrict__ starts, int* __restrict__ nsegp) {
  __shared__ int sh[12];
  __shared__ int s_mode;
  const int md = derive_mode(seg, &s_mode);
  const int bid = blockIdx.x, tid = threadIdx.x;
  const int lane = tid & 63, wid = tid >> 6;
  int part = 0;
  for (int j = tid; j < bid; j += 256) part += blockCounts[j];
  for (int o = 32; o; o >>= 1) part += __shfl_xor(part, o, 64);
  if (lane == 0) sh[wid] = part;
  if (bid == 0) {
    int tot = 0;
    for (int j = tid; j < 576; j += 256) tot += blockCounts[j];
    for (int o = 32; o; o >>= 1) tot += __shfl_xor(tot, o, 64);
    if (lane == 0) sh[8 + wid] = tot;
  }
  const int i = bid * 256 + tid;
  const bool f = is_start(seg, md, i);
  unsigned long long m = __ballot(f);
  if (lane == 0) sh[4 + wid] = __popcll(m);
  __syncthreads();
  const int base = sh[0] + sh[1] + sh[2] + sh[3];
  int wpre = 0;
#pragma unroll
  for (int w2 = 0; w2 < 4; ++w2) if (w2 < wid) wpre += sh[4 + w2];
  if (bid == 0 && tid == 0) *nsegp = sh[8] + sh[9] + sh[10] + sh[11];
  if (f) {
    const int lanePre = __popcll(m & ((1ull << lane) - 1));
    starts[base + wpre + lanePre] = i;
  }
}

// ---------------- 128x128 GEMM tile (dbuf), C = A * B^T (bf16 out) ----------------
__device__ __forceinline__ void gemm_tile(
    const unsigned short* __restrict__ A, const unsigned short* __restrict__ B,
    unsigned short* __restrict__ C, int r0, int c0, int K, int lda, int ldb, int ldc,
    unsigned short* As, unsigned short* Bs) {
  const int tid = threadIdx.x, lane = tid & 63, wid = tid >> 6;
  const int wr = (wid >> 1) * 64, wc = (wid & 1) * 64;
  const int la = lane & 15, lb2 = lane >> 4;
  const int arow = tid >> 2;
  const int cs = ((tid & 3) ^ ((arow >> 1) & 3)) * 8;
  const int nk = K >> 5;
  f32x4 acc[4][4];
#pragma unroll
  for (int i = 0; i < 4; ++i)
#pragma unroll
    for (int j = 0; j < 4; ++j) acc[i][j] = (f32x4)0.0f;

  const unsigned short* ga0 = A + (long)(r0 + arow) * lda + cs;
  const unsigned short* gb0 = B + (long)(c0 + arow) * ldb + cs;

  load_lds16(ga0, &As[tid * 8]);
  load_lds16(ga0 + (long)64 * lda, &As[2048 + tid * 8]);
  load_lds16(gb0, &Bs[tid * 8]);
  load_lds16(gb0 + (long)64 * ldb, &Bs[2048 + tid * 8]);
  __syncthreads();

  for (int k = 0; k < nk; ++k) {
    if (k + 1 < nk) {
      const int nb = ((k + 1) & 1) * 4096;
      const unsigned short* ga = ga0 + (k + 1) * 32;
      const unsigned short* gb = gb0 + (k + 1) * 32;
      load_lds16(ga, &As[nb + tid * 8]);
      load_lds16(ga + (long)64 * lda, &As[nb + 2048 + tid * 8]);
      load_lds16(gb, &Bs[nb + tid * 8]);
      load_lds16(gb + (long)64 * ldb, &Bs[nb + 2048 + tid * 8]);
    }
    const int cb = (k & 1) * 4096;
    bf16x8 af[4], bv[4];
#pragma unroll
    for (int i = 0; i < 4; ++i) {
      const int ra = wr + i * 16 + la;
      const int rb = wc + i * 16 + la;
      af[i] = *reinterpret_cast<const bf16x8*>(&As[cb + ra * 32 + ((lb2 ^ ((ra >> 1) & 3)) * 8)]);
      bv[i] = *reinterpret_cast<const bf16x8*>(&Bs[cb + rb * 32 + ((lb2 ^ ((rb >> 1) & 3)) * 8)]);
    }
#pragma unroll
    for (int i = 0; i < 4; ++i)
#pragma unroll
      for (int j = 0; j < 4; ++j)
        acc[i][j] = __builtin_amdgcn_mfma_f32_16x16x32_bf16(af[i], bv[j], acc[i][j], 0, 0, 0);
    __syncthreads();
  }
#pragma unroll
  for (int i = 0; i < 4; ++i)
#pragma unroll
    for (int j = 0; j < 4; ++j)
#pragma unroll
      for (int r = 0; r < 4; ++r) {
        const int row = r0 + wr + i * 16 + lb2 * 4 + r;
        const int col = c0 + wc + j * 16 + la;
        C[(long)row * ldc + col] = f2bf(acc[i][j][r]);
      }
}

// ---------------- phase 1: all 36 weight combines in one launch ----------------
__global__ __launch_bounds__(256) void k_wgemm(
    const unsigned short* __restrict__ qvgw, const unsigned short* __restrict__ wt,
    const unsigned short* __restrict__ gaw, const unsigned short* __restrict__ owt,
    unsigned short* __restrict__ ABig, unsigned short* __restrict__ Bo2) {
  __shared__ __align__(16) unsigned short As[8192];
  __shared__ __align__(16) unsigned short Bs[8192];
  const int b = blockIdx.z;
  const unsigned short *A, *B;
  unsigned short* C;
  int ldc;
  if (b < 27) {
    A = qvgw + (long)(b / 9) * 65536;          // q_w / v_w / g_w
    B = wt + (long)(b % 9) * 65536;            // scatter_w[p]^T
    C = ABig + (long)b * 65536; ldc = 256;
  } else {
    A = gaw + (long)(b - 27) * 65536;          // gather_w[p]
    B = owt;                                   // o_w^T
    C = Bo2 + (b - 27) * 256; ldc = LDQ;       // Bo2[d][p*256+n]
  }
  gemm_tile(A, B, C, blockIdx.x * 128, blockIdx.y * 128, 256, 256, 256, ldc, As, Bs);
}

// ---------------- phase 2: fused Q/V/G (R9 geometry) + LDS-repack coalesced epilogue ----------------
// 256 thr, BM=128, BN=64, BK=64, 40KB LDS, interleaved X[e][p][w][n].
// Epilogue repacks acc through As (16KB) so stores are 16B/lane, 128B-contiguous per row.
__global__ __launch_bounds__(256) void k_qvg3(
    const unsigned short* __restrict__ ev, const unsigned short* __restrict__ ABig,
    unsigned short* __restrict__ X) {
  __shared__ __align__(16) unsigned short As[8192];       // 128 x 64
  __shared__ __align__(16) unsigned short Bs[3][4096];    // 3 x (64 x 64)
  const int p = blockIdx.z;
  const int r0 = blockIdx.x * 128, c0 = blockIdx.y * 64;
  const int tid = threadIdx.x, lane = tid & 63, wid = tid >> 6;
  const int wr2 = (wid >> 1) * 64, wc2 = (wid & 1) * 32;
  const int la = lane & 15, lb2 = lane >> 4;
  f32x4 acc[3][4][2];
#pragma unroll
  for (int w = 0; w < 3; ++w)
#pragma unroll
    for (int i = 0; i < 4; ++i)
#pragma unroll
      for (int j = 0; j < 2; ++j) acc[w][i][j] = (f32x4)0.0f;

  for (int k0 = 0; k0 < 256; k0 += 64) {
#pragma unroll
    for (int q = 0; q < 4; ++q) {
      const int g = q * 256 + tid;
      const int row = g >> 3, c = g & 7;
      load_lds16(ev + (long)(r0 + row) * 256 + k0 + ((c ^ (row & 7)) * 8), &As[g * 8]);
    }
#pragma unroll
    for (int w = 0; w < 3; ++w) {
      const unsigned short* Bw = ABig + (long)(w * 9 + p) * 65536;
#pragma unroll
      for (int q = 0; q < 2; ++q) {
        const int g = q * 256 + tid;
        const int row = g >> 3, c = g & 7;
        load_lds16(Bw + (long)(c0 + row) * 256 + k0 + ((c ^ (row & 7)) * 8), &Bs[w][g * 8]);
      }
    }
    __syncthreads();
#pragma unroll
    for (int kk = 0; kk < 2; ++kk) {
      bf16x8 af[4], bv[3][2];
#pragma unroll
      for (int i = 0; i < 4; ++i) {
        const int ra = wr2 + i * 16 + la;
        const int slot = (kk * 4 + lb2) ^ (ra & 7);
        af[i] = *reinterpret_cast<const bf16x8*>(&As[ra * 64 + slot * 8]);
      }
#pragma unroll
      for (int w = 0; w < 3; ++w)
#pragma unroll
        for (int j = 0; j < 2; ++j) {
          const int rb = wc2 + j * 16 + la;
          const int slot = (kk * 4 + lb2) ^ (rb & 7);
          bv[w][j] = *reinterpret_cast<const bf16x8*>(&Bs[w][rb * 64 + slot * 8]);
        }
#pragma unroll
      for (int w = 0; w < 3; ++w)
#pragma unroll
        for (int i = 0; i < 4; ++i)
#pragma unroll
          for (int j = 0; j < 2; ++j)
            acc[w][i][j] = __builtin_amdgcn_mfma_f32_16x16x32_bf16(af[i], bv[w][j], acc[w][i][j], 0, 0, 0);
    }
    __syncthreads();
  }
  // repack epilogue: per w, acc -> LDS (swizzled) -> 16B coalesced stores
  for (int w = 0; w < 3; ++w) {
#pragma unroll
    for (int i = 0; i < 4; ++i)
#pragma unroll
      for (int j = 0; j < 2; ++j)
#pragma unroll
        for (int r = 0; r < 4; ++r) {
          const int row = wr2 + i * 16 + lb2 * 4 + r;     // 0..127
          const int col = wc2 + j * 16 + la;              // 0..63
          As[row * 64 + (col ^ ((row & 3) << 3))] = f2bf(acc[w][i][j][r]);
        }
    __syncthreads();
    unsigned short* Xw = X + p * 768 + w * 256;
#pragma unroll
    for (int k = 0; k < 4; ++k) {
      const int cid = k * 256 + tid;                      // 0..1023 chunk id
      const int row = cid >> 3, c = cid & 7;
      bf16x8 vv = *reinterpret_cast<const bf16x8*>(&As[row * 64 + ((c * 8) ^ ((row & 3) << 3))]);
      *reinterpret_cast<bf16x8*>(&Xw[(long)(r0 + row) * LDX + c0 + c * 8]) = vv;
    }
    __syncthreads();
  }
}

// ---------------- gated scan: contiguous 1536B step reads, writes QH over V slot ----------------
__global__ __launch_bounds__(256) void k_scan(
    unsigned short* __restrict__ X,
    const int* __restrict__ starts, const int* __restrict__ cntp,
    const void* __restrict__ seg, const int* __restrict__ pos_id, const int* __restrict__ oidx) {
  __shared__ int s_mode;
  const int md = derive_mode(seg, &s_mode);
  const int lane = threadIdx.x & 63;
  const int w = blockIdx.x * 4 + (threadIdx.x >> 6);
  const int nW = gridDim.x * 4;
  const int nseg = *cntp;
  for (int s = w; s < nseg; s += nW) {
    int t = starts[s];
    int p = pos_id[t], e = oidx[t];
    long base = (long)e * LDX + p * 768 + lane * 4;
    ushort4 ql = *(const ushort4*)(X + base);
    ushort4 vl = *(const ushort4*)(X + base + 256);
    ushort4 gl = *(const ushort4*)(X + base + 512);
    bool cont = (t + 1 < MTOT) && !is_start(seg, md, t + 1);
    float h0 = 0.f, h1 = 0.f, h2 = 0.f, h3 = 0.f;
    for (;;) {
      ushort4 qn, vn, gn;
      long nbase = 0;
      bool cont2 = false;
      if (cont) {
        int pn = pos_id[t + 1], en = oidx[t + 1];
        nbase = (long)en * LDX + pn * 768 + lane * 4;
        qn = *(const ushort4*)(X + nbase);
        vn = *(const ushort4*)(X + nbase + 256);
        gn = *(const ushort4*)(X + nbase + 512);
        cont2 = (t + 2 < MTOT) && !is_start(seg, md, t + 2);
      }
      float g0 = 1.f / (1.f + __expf(-bf2f(gl.x)));
      float g1 = 1.f / (1.f + __expf(-bf2f(gl.y)));
      float g2 = 1.f / (1.f + __expf(-bf2f(gl.z)));
      float g3 = 1.f / (1.f + __expf(-bf2f(gl.w)));
      h0 = g0 * h0 + (1.f - g0) * bf2f(vl.x);
      h1 = g1 * h1 + (1.f - g1) * bf2f(vl.y);
      h2 = g2 * h2 + (1.f - g2) * bf2f(vl.z);
      h3 = g3 * h3 + (1.f - g3) * bf2f(vl.w);
      ushort4 o;
      o.x = f2bf(bf2f(ql.x) * h0);
      o.y = f2bf(bf2f(ql.y) * h1);
      o.z = f2bf(bf2f(ql.z) * h2);
      o.w = f2bf(bf2f(ql.w) * h3);
      *(ushort4*)(X + base + 256) = o;
      if (!cont) break;
      ++t;
      base = nbase; ql = qn; vl = vn; gl = gn; cont = cont2;
    }
  }
}

// ---------------- phase 5: S[e][d] = sum_{p,n} QH[e][p][n]*Bo2[d][p*256+n] + ev[e][d] ----------------
__global__ __launch_bounds__(256) void k_p5(
    const unsigned short* __restrict__ X, const unsigned short* __restrict__ Bo2,
    const float* __restrict__ ev, float* __restrict__ S) {
  __shared__ __align__(16) unsigned short As[4096];
  __shared__ __align__(16) unsigned short Bs[4096];
  const int r0 = blockIdx.x * 128, c0 = blockIdx.y * 128;
  const int tid = threadIdx.x, lane = tid & 63, wid = tid >> 6;
  const int wr = (wid >> 1) * 64, wc = (wid & 1) * 64;
  const int la = lane & 15, lb2 = lane >> 4;
  const int arow = tid >> 2;
  const int cs = ((tid & 3) ^ ((arow >> 1) & 3)) * 8;
  f32x4 acc[4][4];
#pragma unroll
  for (int i = 0; i < 4; ++i)
#pragma unroll
    for (int j = 0; j < 4; ++j) acc[i][j] = (f32x4)0.0f;

  for (int kc = 0; kc < 72; ++kc) {
    const int p = kc >> 3, nn = (kc & 7) * 32;
    const unsigned short* ga = X + (long)(r0 + arow) * LDX + p * 768 + 256 + nn + cs;  // QH slot
    const unsigned short* gb = Bo2 + (long)(c0 + arow) * LDQ + p * 256 + nn + cs;
    load_lds16(ga, &As[tid * 8]);
    load_lds16(ga + (long)64 * LDX, &As[2048 + tid * 8]);
    load_lds16(gb, &Bs[tid * 8]);
    load_lds16(gb + (long)64 * LDQ, &Bs[2048 + tid * 8]);
    __syncthreads();
    bf16x8 af[4], bv[4];
#pragma unroll
    for (int i = 0; i < 4; ++i) {
      const int ra = wr + i * 16 + la;
      const int rb = wc + i * 16 + la;
      af[i] = *reinterpret_cast<const bf16x8*>(&As[ra * 32 + ((lb2 ^ ((ra >> 1) & 3)) * 8)]);
      bv[i] = *reinterpret_cast<const bf16x8*>(&Bs[rb * 32 + ((lb2 ^ ((rb >> 1) & 3)) * 8)]);
    }
#pragma unroll
    for (int i = 0; i < 4; ++i)
#pragma unroll
      for (int j = 0; j < 4; ++j)
        acc[i][j] = __builtin_amdgcn_mfma_f32_16x16x32_bf16(af[i], bv[j], acc[i][j], 0, 0, 0);
    __syncthreads();
  }
#pragma unroll
  for (int i = 0; i < 4; ++i)
#pragma unroll
    for (int j = 0; j < 4; ++j)
#pragma unroll
      for (int r = 0; r < 4; ++r) {
        const int row = r0 + wr + i * 16 + lb2 * 4 + r;
        const int col = c0 + wc + j * 16 + la;
        S[(long)row * 256 + col] = acc[i][j][r] + ev[(long)row * 256 + col];
      }
}

// ---------------- LayerNorm (in place on S, residual already added) ----------------
__global__ __launch_bounds__(256) void k_ln(float* __restrict__ S,
                                            const float* __restrict__ gamma, const float* __restrict__ beta) {
  int row = blockIdx.x * 4 + (threadIdx.x >> 6);
  int lane = threadIdx.x & 63;
  long base = (long)row * 256 + lane * 4;
  float4 s4 = *reinterpret_cast<const float4*>(S + base);
  float v0 = s4.x, v1 = s4.y, v2 = s4.z, v3 = s4.w;
  float s = v0 + v1 + v2 + v3;
  float ss = v0 * v0 + v1 * v1 + v2 * v2 + v3 * v3;
  for (int o = 32; o; o >>= 1) { s += __shfl_xor(s, o, 64); ss += __shfl_xor(ss, o, 64); }
  float mu = s * (1.0f / 256.0f);
  float var = ss * (1.0f / 256.0f) - mu * mu;
  float rs = rsqrtf(fmaxf(var, 0.0f) + 1e-5f);
  float4 g4 = *reinterpret_cast<const float4*>(gamma + lane * 4);
  float4 b4 = *reinterpret_cast<const float4*>(beta + lane * 4);
  float4 o4;
  o4.x = (v0 - mu) * rs * g4.x + b4.x;
  o4.y = (v1 - mu) * rs * g4.y + b4.y;
  o4.z = (v2 - mu) * rs * g4.z + b4.z;
  o4.w = (v3 - mu) * rs * g4.w + b4.w;
  *reinterpret_cast<float4*>(S + base) = o4;
}

extern "C" void kernel_launch(void* const* d_in, const int* in_sizes, int n_in,
                              void* d_out, int out_size, void* d_ws, size_t ws_size,
                              hipStream_t stream) {
  const float* events    = (const float*)d_in[0];
  const float* scatter_w = (const float*)d_in[1];
  const float* gather_w  = (const float*)d_in[2];
  const float* q_w       = (const float*)d_in[3];
  const float* v_w       = (const float*)d_in[4];
  const float* g_w       = (const float*)d_in[5];
  const float* o_w       = (const float*)d_in[6];
  const float* ln_gamma  = (const float*)d_in[7];
  const float* ln_beta   = (const float*)d_in[8];
  const int*   oidx      = (const int*)d_in[9];
  const int*   pos_id    = (const int*)d_in[10];
  const void*  seg       = d_in[11];
  float* out = (float*)d_out;

  // ---- workspace layout (bytes) ----
  char* base = (char*)d_ws;
  int* counter = (int*)base;                                       // 4 (nseg)
  int* blockCounts = (int*)(base + 64);                            // 2304
  int* starts  = (int*)(base + 4096);                              // 589824
  unsigned short* ev_bf  = (unsigned short*)(base + 598016);       // 8388608
  unsigned short* wt     = (unsigned short*)(base + 8986624);      // 1179648 (scatter_w^T)
  unsigned short* qvgw   = (unsigned short*)(base + 10166272);     // 393216
  unsigned short* owt    = (unsigned short*)(base + 10559488);     // 131072 (o_w^T)
  unsigned short* gaw_bf = (unsigned short*)(base + 10690560);     // 1179648
  unsigned short* ABig   = (unsigned short*)(base + 11870208);     // 3538944
  unsigned short* Bo2    = (unsigned short*)(base + 15409152);     // 1179648 [256][2304]
  unsigned short* X      = (unsigned short*)(base + 16588800);     // 226492416 [16384][6912]

  // fused casts + fused transposes
  k_prep<<<4864, 256, 0, stream>>>(events, q_w, v_w, g_w, gather_w, ev_bf, qvgw, gaw_bf);
  k_transpose_t<<<dim3(8, 8, 10), 256, 0, stream>>>(scatter_w, o_w, wt, owt);

  // phase 1: 36 weight combines (27 x ABig, 9 x Bo2)
  k_wgemm<<<dim3(2, 2, 36), 256, 0, stream>>>(qvgw, wt, gaw_bf, owt, ABig, Bo2);

  // phase 2: fused Q/V/G (R9 geometry), interleaved layout, coalesced epilogue
  k_qvg3<<<dim3(128, 4, 9), 256, 0, stream>>>(ev_bf, ABig, X);

  // ordered segment compaction + scan (one segment per wave)
  k_count<<<576, 256, 0, stream>>>(seg, blockCounts);
  k_emit<<<576, 256, 0, stream>>>(seg, blockCounts, starts, counter);
  k_scan<<<4096, 256, 0, stream>>>(X, starts, counter, seg, pos_id, oidx);

  // phase 5 (residual fused) writes directly to d_out; LN in place
  k_p5<<<dim3(128, 2), 256, 0, stream>>>(X, Bo2, events, out);
  k_ln<<<4096, 256, 0, stream>>>(out, ln_gamma, ln_beta);
}

// Round 14
// 217.906 us; speedup vs baseline: 1.0151x; 1.0151x over previous
//
#include <hip/hip_runtime.h>

typedef __bf16 bf16x8 __attribute__((ext_vector_type(8)));
typedef float f32x4 __attribute__((ext_vector_type(4)));

#define NEV 16384
#define MTOT 147456      // NEV * 9
#define LDQ 2304         // Bo2 row stride
#define LDX 6912         // 9 * 3 * 256: X[e][p][{q,v,h}][n]

__device__ __forceinline__ unsigned short f2bf(float f) {
  unsigned x = __float_as_uint(f);
  x += 0x7FFFu + ((x >> 16) & 1u);
  return (unsigned short)(x >> 16);
}
__device__ __forceinline__ float bf2f(unsigned short u) {
  return __uint_as_float(((unsigned)u) << 16);
}
__device__ __forceinline__ void load_lds16(const void* g, void* l) {
  __builtin_amdgcn_global_load_lds(
      (const __attribute__((address_space(1))) unsigned int*)g,
      (__attribute__((address_space(3))) unsigned int*)l, 16, 0, 0);
}

// ---------------- per-block seg_start dtype detection ----------------
__device__ __forceinline__ int derive_mode(const void* seg, int* s_mode) {
  if (threadIdx.x == 0) *s_mode = 0;
  __syncthreads();
  const unsigned int* w = (const unsigned int*)seg;
  int lf = 0, lg = 0;
  for (int i = threadIdx.x; i < 1024; i += blockDim.x) {
    unsigned v = w[i];
    if (v == 0x3F800000u) lf = 1;
    else if (v > 1u) lg = 1;
  }
  if (lf) atomicOr(s_mode, 2);
  if (lg) atomicOr(s_mode, 1);
  __syncthreads();
  int m = *s_mode;
  return (m & 2) ? 2 : ((m & 1) ? 1 : 0);
}

__device__ __forceinline__ bool is_start(const void* seg, int mode, int i) {
  if (mode == 1) return ((const unsigned char*)seg)[i] != 0;
  if (mode == 2) return ((const float*)seg)[i] != 0.0f;
  return ((const int*)seg)[i] != 0;
}

// ---------------- fused casts (events / qvg weights / gather weights) ----------------
__global__ void k_prep(const float* __restrict__ events, const float* __restrict__ q,
                       const float* __restrict__ v, const float* __restrict__ g,
                       const float* __restrict__ gaw,
                       unsigned short* __restrict__ ev_bf, unsigned short* __restrict__ qvgw,
                       unsigned short* __restrict__ gaw_bf) {
  int i = blockIdx.x * blockDim.x + threadIdx.x;
  const float* src;
  unsigned short* dst;
  int off;
  if (i < 1048576) { src = events; dst = ev_bf; off = i; }
  else if (i < 1097728) {
    int j = i - 1048576;
    int w = j >> 14;
    src = (w == 0) ? q : (w == 1) ? v : g;
    dst = qvgw + (long)w * 65536;
    off = j & 16383;
  } else if (i < 1245184) { src = gaw; dst = gaw_bf; off = i - 1097728; }
  else return;
  float4 val = reinterpret_cast<const float4*>(src)[off];
  ushort4 o;
  o.x = f2bf(val.x); o.y = f2bf(val.y); o.z = f2bf(val.z); o.w = f2bf(val.w);
  reinterpret_cast<ushort4*>(dst)[off] = o;
}

// ---------------- LDS-tiled transpose: out[b][r][c] = bf16(in[b][c][r]) ----------------
__global__ __launch_bounds__(256) void k_transpose_t(const float* __restrict__ sw,
                                                     const float* __restrict__ ow,
                                                     unsigned short* __restrict__ wt,
                                                     unsigned short* __restrict__ owt) {
  __shared__ float s[32][33];
  const int z = blockIdx.z;
  const float* src = (z < 9) ? sw + (long)z * 65536 : ow;
  unsigned short* dst = (z < 9) ? wt + (long)z * 65536 : owt;
  const int r0 = blockIdx.x * 32, c0 = blockIdx.y * 32;
  const int tx = threadIdx.x & 31, ty = threadIdx.x >> 5;
#pragma unroll
  for (int cc = 0; cc < 4; ++cc)
    s[ty + cc * 8][tx] = src[(c0 + ty + cc * 8) * 256 + r0 + tx];
  __syncthreads();
#pragma unroll
  for (int cc = 0; cc < 4; ++cc)
    dst[(long)(r0 + ty + cc * 8) * 256 + c0 + tx] = f2bf(s[tx][ty + cc * 8]);
}

// ---------------- ordered segment compaction (deterministic) ----------------
__global__ __launch_bounds__(256) void k_count(const void* __restrict__ seg,
                                               int* __restrict__ blockCounts) {
  __shared__ int wc[4];
  __shared__ int s_mode;
  const int md = derive_mode(seg, &s_mode);
  const int i = blockIdx.x * 256 + threadIdx.x;
  const bool f = is_start(seg, md, i);
  unsigned long long m = __ballot(f);
  const int lane = threadIdx.x & 63, wid = threadIdx.x >> 6;
  if (lane == 0) wc[wid] = __popcll(m);
  __syncthreads();
  if (threadIdx.x == 0) blockCounts[blockIdx.x] = wc[0] + wc[1] + wc[2] + wc[3];
}

__global__ __launch_bounds__(256) void k_emit(const void* __restrict__ seg,
                                              const int* __restrict__ blockCounts,
                                              int* __restrict__ starts, int* __restrict__ nsegp) {
  __shared__ int sh[12];
  __shared__ int s_mode;
  const int md = derive_mode(seg, &s_mode);
  const int bid = blockIdx.x, tid = threadIdx.x;
  const int lane = tid & 63, wid = tid >> 6;
  int part = 0;
  for (int j = tid; j < bid; j += 256) part += blockCounts[j];
  for (int o = 32; o; o >>= 1) part += __shfl_xor(part, o, 64);
  if (lane == 0) sh[wid] = part;
  if (bid == 0) {
    int tot = 0;
    for (int j = tid; j < 576; j += 256) tot += blockCounts[j];
    for (int o = 32; o; o >>= 1) tot += __shfl_xor(tot, o, 64);
    if (lane == 0) sh[8 + wid] = tot;
  }
  const int i = bid * 256 + tid;
  const bool f = is_start(seg, md, i);
  unsigned long long m = __ballot(f);
  if (lane == 0) sh[4 + wid] = __popcll(m);
  __syncthreads();
  const int base = sh[0] + sh[1] + sh[2] + sh[3];
  int wpre = 0;
#pragma unroll
  for (int w2 = 0; w2 < 4; ++w2) if (w2 < wid) wpre += sh[4 + w2];
  if (bid == 0 && tid == 0) *nsegp = sh[8] + sh[9] + sh[10] + sh[11];
  if (f) {
    const int lanePre = __popcll(m & ((1ull << lane) - 1));
    starts[base + wpre + lanePre] = i;
  }
}

// ---------------- 128x128 GEMM tile (dbuf), C = A * B^T (bf16 out) ----------------
__device__ __forceinline__ void gemm_tile(
    const unsigned short* __restrict__ A, const unsigned short* __restrict__ B,
    unsigned short* __restrict__ C, int r0, int c0, int K, int lda, int ldb, int ldc,
    unsigned short* As, unsigned short* Bs) {
  const int tid = threadIdx.x, lane = tid & 63, wid = tid >> 6;
  const int wr = (wid >> 1) * 64, wc = (wid & 1) * 64;
  const int la = lane & 15, lb2 = lane >> 4;
  const int arow = tid >> 2;
  const int cs = ((tid & 3) ^ ((arow >> 1) & 3)) * 8;
  const int nk = K >> 5;
  f32x4 acc[4][4];
#pragma unroll
  for (int i = 0; i < 4; ++i)
#pragma unroll
    for (int j = 0; j < 4; ++j) acc[i][j] = (f32x4)0.0f;

  const unsigned short* ga0 = A + (long)(r0 + arow) * lda + cs;
  const unsigned short* gb0 = B + (long)(c0 + arow) * ldb + cs;

  load_lds16(ga0, &As[tid * 8]);
  load_lds16(ga0 + (long)64 * lda, &As[2048 + tid * 8]);
  load_lds16(gb0, &Bs[tid * 8]);
  load_lds16(gb0 + (long)64 * ldb, &Bs[2048 + tid * 8]);
  __syncthreads();

  for (int k = 0; k < nk; ++k) {
    if (k + 1 < nk) {
      const int nb = ((k + 1) & 1) * 4096;
      const unsigned short* ga = ga0 + (k + 1) * 32;
      const unsigned short* gb = gb0 + (k + 1) * 32;
      load_lds16(ga, &As[nb + tid * 8]);
      load_lds16(ga + (long)64 * lda, &As[nb + 2048 + tid * 8]);
      load_lds16(gb, &Bs[nb + tid * 8]);
      load_lds16(gb + (long)64 * ldb, &Bs[nb + 2048 + tid * 8]);
    }
    const int cb = (k & 1) * 4096;
    bf16x8 af[4], bv[4];
#pragma unroll
    for (int i = 0; i < 4; ++i) {
      const int ra = wr + i * 16 + la;
      const int rb = wc + i * 16 + la;
      af[i] = *reinterpret_cast<const bf16x8*>(&As[cb + ra * 32 + ((lb2 ^ ((ra >> 1) & 3)) * 8)]);
      bv[i] = *reinterpret_cast<const bf16x8*>(&Bs[cb + rb * 32 + ((lb2 ^ ((rb >> 1) & 3)) * 8)]);
    }
#pragma unroll
    for (int i = 0; i < 4; ++i)
#pragma unroll
      for (int j = 0; j < 4; ++j)
        acc[i][j] = __builtin_amdgcn_mfma_f32_16x16x32_bf16(af[i], bv[j], acc[i][j], 0, 0, 0);
    __syncthreads();
  }
#pragma unroll
  for (int i = 0; i < 4; ++i)
#pragma unroll
    for (int j = 0; j < 4; ++j)
#pragma unroll
      for (int r = 0; r < 4; ++r) {
        const int row = r0 + wr + i * 16 + lb2 * 4 + r;
        const int col = c0 + wc + j * 16 + la;
        C[(long)row * ldc + col] = f2bf(acc[i][j][r]);
      }
}

// ---------------- phase 1: all 36 weight combines in one launch ----------------
__global__ __launch_bounds__(256) void k_wgemm(
    const unsigned short* __restrict__ qvgw, const unsigned short* __restrict__ wt,
    const unsigned short* __restrict__ gaw, const unsigned short* __restrict__ owt,
    unsigned short* __restrict__ ABig, unsigned short* __restrict__ Bo2) {
  __shared__ __align__(16) unsigned short As[8192];
  __shared__ __align__(16) unsigned short Bs[8192];
  const int b = blockIdx.z;
  const unsigned short *A, *B;
  unsigned short* C;
  int ldc;
  if (b < 27) {
    A = qvgw + (long)(b / 9) * 65536;          // q_w / v_w / g_w
    B = wt + (long)(b % 9) * 65536;            // scatter_w[p]^T
    C = ABig + (long)b * 65536; ldc = 256;
  } else {
    A = gaw + (long)(b - 27) * 65536;          // gather_w[p]
    B = owt;                                   // o_w^T
    C = Bo2 + (b - 27) * 256; ldc = LDQ;       // Bo2[d][p*256+n]
  }
  gemm_tile(A, B, C, blockIdx.x * 128, blockIdx.y * 128, 256, 256, 256, ldc, As, Bs);
}

// ---------------- phase 2: fused Q/V/G (R9 geometry), A-panel-locality grid order ----------------
// Flat grid 4608: bid = xs*36 + (p*4 + cy). The 36 sharers of A-panel xs run
// concurrently -> panel fetched ~once (L3 absorbs cross-XCD), writes cover
// contiguous X rows. 256 thr, BM=128, BN=64, BK=64, 40KB LDS.
__global__ __launch_bounds__(256) void k_qvg3(
    const unsigned short* __restrict__ ev, const unsigned short* __restrict__ ABig,
    unsigned short* __restrict__ X) {
  __shared__ __align__(16) unsigned short As[8192];       // 128 x 64
  __shared__ __align__(16) unsigned short Bs[3][4096];    // 3 x (64 x 64)
  const int bid = blockIdx.x;
  const int xs = bid / 36;
  const int yz = bid % 36;
  const int p = yz >> 2;
  const int r0 = xs * 128, c0 = (yz & 3) * 64;
  const int tid = threadIdx.x, lane = tid & 63, wid = tid >> 6;
  const int wr2 = (wid >> 1) * 64, wc2 = (wid & 1) * 32;
  const int la = lane & 15, lb2 = lane >> 4;
  f32x4 acc[3][4][2];
#pragma unroll
  for (int w = 0; w < 3; ++w)
#pragma unroll
    for (int i = 0; i < 4; ++i)
#pragma unroll
      for (int j = 0; j < 2; ++j) acc[w][i][j] = (f32x4)0.0f;

  for (int k0 = 0; k0 < 256; k0 += 64) {
#pragma unroll
    for (int q = 0; q < 4; ++q) {
      const int g = q * 256 + tid;
      const int row = g >> 3, c = g & 7;
      load_lds16(ev + (long)(r0 + row) * 256 + k0 + ((c ^ (row & 7)) * 8), &As[g * 8]);
    }
#pragma unroll
    for (int w = 0; w < 3; ++w) {
      const unsigned short* Bw = ABig + (long)(w * 9 + p) * 65536;
#pragma unroll
      for (int q = 0; q < 2; ++q) {
        const int g = q * 256 + tid;
        const int row = g >> 3, c = g & 7;
        load_lds16(Bw + (long)(c0 + row) * 256 + k0 + ((c ^ (row & 7)) * 8), &Bs[w][g * 8]);
      }
    }
    __syncthreads();
#pragma unroll
    for (int kk = 0; kk < 2; ++kk) {
      bf16x8 af[4], bv[3][2];
#pragma unroll
      for (int i = 0; i < 4; ++i) {
        const int ra = wr2 + i * 16 + la;
        const int slot = (kk * 4 + lb2) ^ (ra & 7);
        af[i] = *reinterpret_cast<const bf16x8*>(&As[ra * 64 + slot * 8]);
      }
#pragma unroll
      for (int w = 0; w < 3; ++w)
#pragma unroll
        for (int j = 0; j < 2; ++j) {
          const int rb = wc2 + j * 16 + la;
          const int slot = (kk * 4 + lb2) ^ (rb & 7);
          bv[w][j] = *reinterpret_cast<const bf16x8*>(&Bs[w][rb * 64 + slot * 8]);
        }
#pragma unroll
      for (int w = 0; w < 3; ++w)
#pragma unroll
        for (int i = 0; i < 4; ++i)
#pragma unroll
          for (int j = 0; j < 2; ++j)
            acc[w][i][j] = __builtin_amdgcn_mfma_f32_16x16x32_bf16(af[i], bv[w][j], acc[w][i][j], 0, 0, 0);
    }
    __syncthreads();
  }
  // R12 scalar-store epilogue (LDS-repack was measured null, reverted)
#pragma unroll
  for (int w = 0; w < 3; ++w) {
    unsigned short* Xw = X + p * 768 + w * 256;
#pragma unroll
    for (int i = 0; i < 4; ++i)
#pragma unroll
      for (int j = 0; j < 2; ++j)
#pragma unroll
        for (int r = 0; r < 4; ++r) {
          const int row = r0 + wr2 + i * 16 + lb2 * 4 + r;
          const int col = c0 + wc2 + j * 16 + la;
          Xw[(long)row * LDX + col] = f2bf(acc[w][i][j][r]);
        }
  }
}

// ---------------- gated scan: contiguous 1536B step reads, writes QH over V slot ----------------
__global__ __launch_bounds__(256) void k_scan(
    unsigned short* __restrict__ X,
    const int* __restrict__ starts, const int* __restrict__ cntp,
    const void* __restrict__ seg, const int* __restrict__ pos_id, const int* __restrict__ oidx) {
  __shared__ int s_mode;
  const int md = derive_mode(seg, &s_mode);
  const int lane = threadIdx.x & 63;
  const int w = blockIdx.x * 4 + (threadIdx.x >> 6);
  const int nW = gridDim.x * 4;
  const int nseg = *cntp;
  for (int s = w; s < nseg; s += nW) {
    int t = starts[s];
    int p = pos_id[t], e = oidx[t];
    long base = (long)e * LDX + p * 768 + lane * 4;
    ushort4 ql = *(const ushort4*)(X + base);
    ushort4 vl = *(const ushort4*)(X + base + 256);
    ushort4 gl = *(const ushort4*)(X + base + 512);
    bool cont = (t + 1 < MTOT) && !is_start(seg, md, t + 1);
    float h0 = 0.f, h1 = 0.f, h2 = 0.f, h3 = 0.f;
    for (;;) {
      ushort4 qn, vn, gn;
      long nbase = 0;
      bool cont2 = false;
      if (cont) {
        int pn = pos_id[t + 1], en = oidx[t + 1];
        nbase = (long)en * LDX + pn * 768 + lane * 4;
        qn = *(const ushort4*)(X + nbase);
        vn = *(const ushort4*)(X + nbase + 256);
        gn = *(const ushort4*)(X + nbase + 512);
        cont2 = (t + 2 < MTOT) && !is_start(seg, md, t + 2);
      }
      float g0 = 1.f / (1.f + __expf(-bf2f(gl.x)));
      float g1 = 1.f / (1.f + __expf(-bf2f(gl.y)));
      float g2 = 1.f / (1.f + __expf(-bf2f(gl.z)));
      float g3 = 1.f / (1.f + __expf(-bf2f(gl.w)));
      h0 = g0 * h0 + (1.f - g0) * bf2f(vl.x);
      h1 = g1 * h1 + (1.f - g1) * bf2f(vl.y);
      h2 = g2 * h2 + (1.f - g2) * bf2f(vl.z);
      h3 = g3 * h3 + (1.f - g3) * bf2f(vl.w);
      ushort4 o;
      o.x = f2bf(bf2f(ql.x) * h0);
      o.y = f2bf(bf2f(ql.y) * h1);
      o.z = f2bf(bf2f(ql.z) * h2);
      o.w = f2bf(bf2f(ql.w) * h3);
      *(ushort4*)(X + base + 256) = o;
      if (!cont) break;
      ++t;
      base = nbase; ql = qn; vl = vn; gl = gn; cont = cont2;
    }
  }
}

// ---------------- phase 5: S[e][d] = sum_{p,n} QH[e][p][n]*Bo2[d][p*256+n] + ev[e][d] ----------------
__global__ __launch_bounds__(256) void k_p5(
    const unsigned short* __restrict__ X, const unsigned short* __restrict__ Bo2,
    const float* __restrict__ ev, float* __restrict__ S) {
  __shared__ __align__(16) unsigned short As[4096];
  __shared__ __align__(16) unsigned short Bs[4096];
  const int r0 = blockIdx.x * 128, c0 = blockIdx.y * 128;
  const int tid = threadIdx.x, lane = tid & 63, wid = tid >> 6;
  const int wr = (wid >> 1) * 64, wc = (wid & 1) * 64;
  const int la = lane & 15, lb2 = lane >> 4;
  const int arow = tid >> 2;
  const int cs = ((tid & 3) ^ ((arow >> 1) & 3)) * 8;
  f32x4 acc[4][4];
#pragma unroll
  for (int i = 0; i < 4; ++i)
#pragma unroll
    for (int j = 0; j < 4; ++j) acc[i][j] = (f32x4)0.0f;

  for (int kc = 0; kc < 72; ++kc) {
    const int p = kc >> 3, nn = (kc & 7) * 32;
    const unsigned short* ga = X + (long)(r0 + arow) * LDX + p * 768 + 256 + nn + cs;  // QH slot
    const unsigned short* gb = Bo2 + (long)(c0 + arow) * LDQ + p * 256 + nn + cs;
    load_lds16(ga, &As[tid * 8]);
    load_lds16(ga + (long)64 * LDX, &As[2048 + tid * 8]);
    load_lds16(gb, &Bs[tid * 8]);
    load_lds16(gb + (long)64 * LDQ, &Bs[2048 + tid * 8]);
    __syncthreads();
    bf16x8 af[4], bv[4];
#pragma unroll
    for (int i = 0; i < 4; ++i) {
      const int ra = wr + i * 16 + la;
      const int rb = wc + i * 16 + la;
      af[i] = *reinterpret_cast<const bf16x8*>(&As[ra * 32 + ((lb2 ^ ((ra >> 1) & 3)) * 8)]);
      bv[i] = *reinterpret_cast<const bf16x8*>(&Bs[rb * 32 + ((lb2 ^ ((rb >> 1) & 3)) * 8)]);
    }
#pragma unroll
    for (int i = 0; i < 4; ++i)
#pragma unroll
      for (int j = 0; j < 4; ++j)
        acc[i][j] = __builtin_amdgcn_mfma_f32_16x16x32_bf16(af[i], bv[j], acc[i][j], 0, 0, 0);
    __syncthreads();
  }
#pragma unroll
  for (int i = 0; i < 4; ++i)
#pragma unroll
    for (int j = 0; j < 4; ++j)
#pragma unroll
      for (int r = 0; r < 4; ++r) {
        const int row = r0 + wr + i * 16 + lb2 * 4 + r;
        const int col = c0 + wc + j * 16 + la;
        S[(long)row * 256 + col] = acc[i][j][r] + ev[(long)row * 256 + col];
      }
}

// ---------------- LayerNorm (in place on S, residual already added) ----------------
__global__ __launch_bounds__(256) void k_ln(float* __restrict__ S,
                                            const float* __restrict__ gamma, const float* __restrict__ beta) {
  int row = blockIdx.x * 4 + (threadIdx.x >> 6);
  int lane = threadIdx.x & 63;
  long base = (long)row * 256 + lane * 4;
  float4 s4 = *reinterpret_cast<const float4*>(S + base);
  float v0 = s4.x, v1 = s4.y, v2 = s4.z, v3 = s4.w;
  float s = v0 + v1 + v2 + v3;
  float ss = v0 * v0 + v1 * v1 + v2 * v2 + v3 * v3;
  for (int o = 32; o; o >>= 1) { s += __shfl_xor(s, o, 64); ss += __shfl_xor(ss, o, 64); }
  float mu = s * (1.0f / 256.0f);
  float var = ss * (1.0f / 256.0f) - mu * mu;
  float rs = rsqrtf(fmaxf(var, 0.0f) + 1e-5f);
  float4 g4 = *reinterpret_cast<const float4*>(gamma + lane * 4);
  float4 b4 = *reinterpret_cast<const float4*>(beta + lane * 4);
  float4 o4;
  o4.x = (v0 - mu) * rs * g4.x + b4.x;
  o4.y = (v1 - mu) * rs * g4.y + b4.y;
  o4.z = (v2 - mu) * rs * g4.z + b4.z;
  o4.w = (v3 - mu) * rs * g4.w + b4.w;
  *reinterpret_cast<float4*>(S + base) = o4;
}

extern "C" void kernel_launch(void* const* d_in, const int* in_sizes, int n_in,
                              void* d_out, int out_size, void* d_ws, size_t ws_size,
                              hipStream_t stream) {
  const float* events    = (const float*)d_in[0];
  const float* scatter_w = (const float*)d_in[1];
  const float* gather_w  = (const float*)d_in[2];
  const float* q_w       = (const float*)d_in[3];
  const float* v_w       = (const float*)d_in[4];
  const float* g_w       = (const float*)d_in[5];
  const float* o_w       = (const float*)d_in[6];
  const float* ln_gamma  = (const float*)d_in[7];
  const float* ln_beta   = (const float*)d_in[8];
  const int*   oidx      = (const int*)d_in[9];
  const int*   pos_id    = (const int*)d_in[10];
  const void*  seg       = d_in[11];
  float* out = (float*)d_out;

  // ---- workspace layout (bytes) ----
  char* base = (char*)d_ws;
  int* counter = (int*)base;                                       // 4 (nseg)
  int* blockCounts = (int*)(base + 64);                            // 2304
  int* starts  = (int*)(base + 4096);                              // 589824
  unsigned short* ev_bf  = (unsigned short*)(base + 598016);       // 8388608
  unsigned short* wt     = (unsigned short*)(base + 8986624);      // 1179648 (scatter_w^T)
  unsigned short* qvgw   = (unsigned short*)(base + 10166272);     // 393216
  unsigned short* owt    = (unsigned short*)(base + 10559488);     // 131072 (o_w^T)
  unsigned short* gaw_bf = (unsigned short*)(base + 10690560);     // 1179648
  unsigned short* ABig   = (unsigned short*)(base + 11870208);     // 3538944
  unsigned short* Bo2    = (unsigned short*)(base + 15409152);     // 1179648 [256][2304]
  unsigned short* X      = (unsigned short*)(base + 16588800);     // 226492416 [16384][6912]

  // fused casts + fused transposes
  k_prep<<<4864, 256, 0, stream>>>(events, q_w, v_w, g_w, gather_w, ev_bf, qvgw, gaw_bf);
  k_transpose_t<<<dim3(8, 8, 10), 256, 0, stream>>>(scatter_w, o_w, wt, owt);

  // phase 1: 36 weight combines (27 x ABig, 9 x Bo2)
  k_wgemm<<<dim3(2, 2, 36), 256, 0, stream>>>(qvgw, wt, gaw_bf, owt, ABig, Bo2);

  // phase 2: fused Q/V/G, A-panel-locality flat grid
  k_qvg3<<<4608, 256, 0, stream>>>(ev_bf, ABig, X);

  // ordered segment compaction + scan (one segment per wave)
  k_count<<<576, 256, 0, stream>>>(seg, blockCounts);
  k_emit<<<576, 256, 0, stream>>>(seg, blockCounts, starts, counter);
  k_scan<<<4096, 256, 0, stream>>>(X, starts, counter, seg, pos_id, oidx);

  // phase 5 (residual fused) writes directly to d_out; LN in place
  k_p5<<<dim3(128, 2), 256, 0, stream>>>(X, Bo2, events, out);
  k_ln<<<4096, 256, 0, stream>>>(out, ln_gamma, ln_beta);
}